// Round 3
// baseline (292.032 us; speedup 1.0000x reference)
//
#include <hip/hip_runtime.h>
#include <math.h>

// Problem constants (fixed by the reference)
#define MM 12       // M
#define KK 2        // K
#define DD 512      // D
#define CIN 4096    // C_IN
#define NCLS 8
#define NV 16       // N (videos) == LSTM step count
#define TT 32       // T
// Only LSTM batch row t=31 is ever consumed (rows independent; out uses hs[:, -1, :]).

typedef unsigned long long u64;

// ws layout (floats) — same 3.375 MB budget proven in R1/R2
#define PART_F   0                    // 4 * 192 * 1024 (split-K partials, [ks][j][o])
#define POOLED_F 786432               // 16*512
#define GX_F     794624               // 16*2048
#define SLOT_F   827392               // 16 steps * 512 dims * 2 (u64 tagged {h,tag})

// ---------------------------------------------------------------------------
// Kernel 1: split-K GEMM  part[ks][j][o] += w_a[o,cc] * base_sel[j,cc]
// Tiles: 64(o) x 48(j), 4 K-splits of 1024, 16 cc staged per iter, software
// prefetch (load it+1 while computing it). Grid 4x16x4 = 256 WGs = 1/CU.
// ---------------------------------------------------------------------------
__global__ __launch_bounds__(256) void k_gemm(const float* __restrict__ w_a,
                                              const float* __restrict__ base_out,
                                              float* __restrict__ part) {
    const int ks = blockIdx.x;   // 0..3
    const int ot = blockIdx.y;   // 0..15
    const int jt = blockIdx.z;   // 0..3 (j-tile of 48)
    const int tid = threadIdx.x;

    __shared__ __align__(16) float As[16][68];
    __shared__ __align__(16) float Bs[16][52];

    const int to = tid & 15;     // o micro (4 consecutive o)
    const int tj = tid >> 4;     // j micro base (j = 48jt + tj + 16jj)

    // staging roles
    const int arow = tid >> 2;   // 0..63 (o row)
    const int aq   = tid & 3;    // cc quad
    const size_t a_base = (size_t)(ot * 64 + arow) * CIN;

    const int brow = tid >> 2;   // 0..47 valid when tid<192 (j row)
    const int j_stage = jt * 48 + brow;
    const int n_stage = j_stage / 12;
    const int m_stage = j_stage - n_stage * 12;
    const size_t b_base = (size_t)((n_stage * TT + 31) * MM + m_stage) * CIN;

    float acc[4][3];
#pragma unroll
    for (int i = 0; i < 4; ++i)
#pragma unroll
        for (int jj = 0; jj < 3; ++jj) acc[i][jj] = 0.f;

    int cc0 = ks * 1024;
    float4 av = *(const float4*)&w_a[a_base + cc0 + aq * 4];
    float4 bv;
    if (tid < 192) bv = *(const float4*)&base_out[b_base + cc0 + aq * 4];

    for (int it = 0; it < 64; ++it) {
        __syncthreads();
        As[aq * 4 + 0][arow] = av.x; As[aq * 4 + 1][arow] = av.y;
        As[aq * 4 + 2][arow] = av.z; As[aq * 4 + 3][arow] = av.w;
        if (tid < 192) {
            Bs[aq * 4 + 0][brow] = bv.x; Bs[aq * 4 + 1][brow] = bv.y;
            Bs[aq * 4 + 2][brow] = bv.z; Bs[aq * 4 + 3][brow] = bv.w;
        }
        __syncthreads();
        if (it < 63) {   // prefetch next stage; latency hides under compute
            cc0 += 16;
            av = *(const float4*)&w_a[a_base + cc0 + aq * 4];
            if (tid < 192) bv = *(const float4*)&base_out[b_base + cc0 + aq * 4];
        }
#pragma unroll
        for (int cl = 0; cl < 16; ++cl) {
            float4 a = *(const float4*)&As[cl][to * 4];
            float b0 = Bs[cl][tj];
            float b1 = Bs[cl][tj + 16];
            float b2 = Bs[cl][tj + 32];
            acc[0][0] += a.x * b0; acc[0][1] += a.x * b1; acc[0][2] += a.x * b2;
            acc[1][0] += a.y * b0; acc[1][1] += a.y * b1; acc[1][2] += a.y * b2;
            acc[2][0] += a.z * b0; acc[2][1] += a.z * b1; acc[2][2] += a.z * b2;
            acc[3][0] += a.w * b0; acc[3][1] += a.w * b1; acc[3][2] += a.w * b2;
        }
    }

    const int o_base = ot * 64 + to * 4;
#pragma unroll
    for (int jj = 0; jj < 3; ++jj) {
        const int j = jt * 48 + tj + 16 * jj;
        float4 v = make_float4(acc[0][jj], acc[1][jj], acc[2][jj], acc[3][jj]);
        *(float4*)&part[(size_t)ks * (192 * 1024) + (size_t)j * 1024 + o_base] = v;
    }
}

// ---------------------------------------------------------------------------
// Kernel 2: reduce split-K partials, contract with A=sum_p dist[n,31,p,k,:,:],
//           relu, mean over w -> pooled[n, c].  One WG per n.
// ---------------------------------------------------------------------------
__global__ __launch_bounds__(256) void k_pool(const float* __restrict__ part,
                                              const float* __restrict__ dist,
                                              float* __restrict__ pooled) {
    const int n = blockIdx.x;
    const int tid = threadIdx.x;
    __shared__ float Asum[KK][MM][MM];

    const size_t dbase = (size_t)(n * TT + 31) * (3 * KK * MM * MM);
    for (int f = tid; f < KK * MM * MM; f += 256) {
        const int k = f / (MM * MM);
        const int rem = f - k * (MM * MM);
        float s = dist[dbase + 0 * (KK * MM * MM) + k * (MM * MM) + rem]
                + dist[dbase + 1 * (KK * MM * MM) + k * (MM * MM) + rem]
                + dist[dbase + 2 * (KK * MM * MM) + k * (MM * MM) + rem];
        Asum[k][rem / MM][rem % MM] = s;
    }
    __syncthreads();

    for (int c = tid; c < DD; c += 256) {
        float nd[KK][MM];
#pragma unroll
        for (int k = 0; k < KK; ++k)
#pragma unroll
            for (int v = 0; v < MM; ++v) {
                const size_t off = (size_t)(n * MM + v) * 1024 + (k * DD + c);
                nd[k][v] = part[off] + part[off + 1 * (192 * 1024)]
                         + part[off + 2 * (192 * 1024)] + part[off + 3 * (192 * 1024)];
            }
        float accm = 0.f;
#pragma unroll
        for (int w = 0; w < MM; ++w) {
            float sw = 0.f;
#pragma unroll
            for (int k = 0; k < KK; ++k)
#pragma unroll
                for (int v = 0; v < MM; ++v) sw += nd[k][v] * Asum[k][v][w];
            accm += fmaxf(sw, 0.f);
        }
        pooled[n * DD + c] = accm * (1.f / 12.f);
    }
}

// ---------------------------------------------------------------------------
// Kernel 3: gx[n, r] = pooled[n,:] . w_ih[r,:] + b_ih[r] + b_hh[r]
// 128 WGs; WG wg caches w_ih rows [16wg,16wg+16) in LDS (read once device-wide).
// ---------------------------------------------------------------------------
__global__ __launch_bounds__(256) void k_gx(const float* __restrict__ pooled,
                                            const float* __restrict__ w_ih,
                                            const float* __restrict__ b_ih,
                                            const float* __restrict__ b_hh,
                                            float* __restrict__ gx) {
    const int wg = blockIdx.x;   // 0..127
    const int tid = threadIdx.x;
    __shared__ __align__(16) float w_s[16][516];

    for (int f = tid; f < 16 * DD; f += 256) {
        const int r = f >> 9, col = f & 511;
        w_s[r][col] = w_ih[(size_t)(wg * 16 + r) * DD + col];
    }
    __syncthreads();

    const int r = tid & 15;
    const int n = tid >> 4;
    const float4* wr = (const float4*)&w_s[r][0];
    const float4* pv = (const float4*)(pooled + n * DD);
    float acc = 0.f;
#pragma unroll 8
    for (int q = 0; q < DD / 4; ++q) {
        float4 a = wr[q], b = pv[q];
        acc += a.x * b.x + a.y * b.y + a.z * b.z + a.w * b.w;
    }
    const int row = wg * 16 + r;
    gx[n * (4 * DD) + row] = acc + b_ih[row] + b_hh[row];
}

// ---------------------------------------------------------------------------
// Kernel 4: LSTM via tagged dataflow. 32 WGs x 256 threads; WG wg owns h-dims
// [16wg, 16wg+16) (64 w_hh rows = 132 KB LDS). 4x fewer pollers/producers than
// R2. Publish = 64-bit relaxed agent atomic {h, tag=s+1}; poll w/ s_sleep.
// ---------------------------------------------------------------------------
__global__ __launch_bounds__(256) void k_lstm(const float* __restrict__ w_hh,
                                              const float* __restrict__ gx,
                                              const float* __restrict__ w_cls,
                                              const float* __restrict__ b_cls,
                                              u64* __restrict__ slots,   // 16*512
                                              float* __restrict__ out) {
    const int wg = blockIdx.x;   // 0..31
    const int tid = threadIdx.x;

    __shared__ __align__(16) float whh_s[64][516];  // rl = gate*16 + dl
    __shared__ __align__(16) float h_s[DD];
    __shared__ float dot_s[64];

    // preload 64 rows (float4-vectorized, coalesced): w_hh row gate*512+16wg+dl
    for (int f = tid; f < 64 * 128; f += 256) {
        const int rl = f >> 7, q = f & 127;
        const int gate = rl >> 4, dl = rl & 15;
        float4 v = *(const float4*)&w_hh[(size_t)(gate * DD + wg * 16 + dl) * DD + q * 4];
        *(float4*)&whh_s[rl][q * 4] = v;
    }

    float c_reg = 0.f;
    const int r  = tid >> 2;     // row 0..63
    const int lp = tid & 3;      // slice 0..3 (128 elems each)

    for (int s = 0; s < NV; ++s) {
        if (s == 0) {
            for (int d = tid; d < DD; d += 256) h_s[d] = 0.f;
        } else {
            const u64* slot = slots + (size_t)(s - 1) * DD;
            for (int d = tid; d < DD; d += 256) {
                u64 v = __hip_atomic_load(&slot[d], __ATOMIC_RELAXED, __HIP_MEMORY_SCOPE_AGENT);
                while ((unsigned)(v & 0xffffffffull) != (unsigned)s) {
                    __builtin_amdgcn_s_sleep(1);
                    v = __hip_atomic_load(&slot[d], __ATOMIC_RELAXED, __HIP_MEMORY_SCOPE_AGENT);
                }
                union { unsigned u; float f; } cv; cv.u = (unsigned)(v >> 32);
                h_s[d] = cv.f;
            }
        }
        __syncthreads();   // also covers whh_s preload before first use

        // 64 row-dots, 4 lanes per row, interleaved float4 slices.
        // Bank math: addr%32 of whh_s[r][4(lp+4q)] = (4(r+lp)+16q)%32 ->
        // 8 lanes per 4-bank group = balanced = baseline b128 cost.
        float p = 0.f;
        const float4* wrow = (const float4*)&whh_s[r][0];
        const float4* hv4 = (const float4*)h_s;
#pragma unroll
        for (int q = 0; q < 32; ++q) {
            float4 wv = wrow[lp + 4 * q];
            float4 hv = hv4[lp + 4 * q];
            p += wv.x * hv.x + wv.y * hv.y + wv.z * hv.z + wv.w * hv.w;
        }
        p += __shfl_down(p, 2, 4);
        p += __shfl_down(p, 1, 4);
        if (lp == 0) dot_s[r] = p;
        __syncthreads();

        if (tid < 16) {
            const int dg = wg * 16 + tid;
            const float* gxs = gx + s * (4 * DD);
            const float pi = gxs[0 * DD + dg] + dot_s[0  + tid];
            const float pf = gxs[1 * DD + dg] + dot_s[16 + tid];
            const float pg = gxs[2 * DD + dg] + dot_s[32 + tid];
            const float po = gxs[3 * DD + dg] + dot_s[48 + tid];
            const float si = 1.f / (1.f + expf(-pi));
            const float sf = 1.f / (1.f + expf(-pf));
            const float so = 1.f / (1.f + expf(-po));
            c_reg = sf * c_reg + si * tanhf(pg);
            const float hn = so * tanhf(c_reg);
            union { float f; unsigned u; } hv_; hv_.f = hn;
            const u64 pack = ((u64)hv_.u << 32) | (u64)(unsigned)(s + 1);
            __hip_atomic_store(&slots[(size_t)s * DD + dg], pack,
                               __ATOMIC_RELAXED, __HIP_MEMORY_SCOPE_AGENT);
        }
        // safe: h_s/dot_s only rewritten after the next top/post-dot syncs.
    }

    // classifier tail: out[n,cl] = h_n . w_cls[cl,:] + b_cls[cl]
    if (wg == 0) {
        for (int f = tid; f < NV * DD; f += 256) {
            const int ss = f >> 9, d = f & 511;
            u64 v = __hip_atomic_load(&slots[(size_t)ss * DD + d],
                                      __ATOMIC_RELAXED, __HIP_MEMORY_SCOPE_AGENT);
            while ((unsigned)(v & 0xffffffffull) != (unsigned)(ss + 1)) {
                __builtin_amdgcn_s_sleep(1);
                v = __hip_atomic_load(&slots[(size_t)ss * DD + d],
                                      __ATOMIC_RELAXED, __HIP_MEMORY_SCOPE_AGENT);
            }
            union { unsigned u; float f; } cv; cv.u = (unsigned)(v >> 32);
            whh_s[ss][d] = cv.f;   // reuse rows 0..15 as h staging
        }
        __syncthreads();
        if (tid < NV * NCLS) {
            const int n = tid >> 3, cl = tid & 7;
            const float4* hv = (const float4*)&whh_s[n][0];
            const float4* wv = (const float4*)(w_cls + (size_t)cl * DD);
            float acc = b_cls[cl];
#pragma unroll 8
            for (int q = 0; q < DD / 4; ++q) {
                float4 a = hv[q], b = wv[q];
                acc += a.x * b.x + a.y * b.y + a.z * b.z + a.w * b.w;
            }
            out[tid] = acc;
        }
    }
}

extern "C" void kernel_launch(void* const* d_in, const int* in_sizes, int n_in,
                              void* d_out, int out_size, void* d_ws, size_t ws_size,
                              hipStream_t stream) {
    const float* base_out = (const float*)d_in[0];
    const float* dist     = (const float*)d_in[1];
    const float* w_a      = (const float*)d_in[2];
    const float* w_ih     = (const float*)d_in[3];
    const float* w_hh     = (const float*)d_in[4];
    const float* b_ih     = (const float*)d_in[5];
    const float* b_hh     = (const float*)d_in[6];
    const float* w_cls    = (const float*)d_in[7];
    const float* b_cls    = (const float*)d_in[8];
    float* out = (float*)d_out;

    float* ws = (float*)d_ws;
    float* part   = ws + PART_F;
    float* pooled = ws + POOLED_F;
    float* gx     = ws + GX_F;
    u64*   slots  = (u64*)(ws + SLOT_F);
    // No memset needed: tags self-validate (0xAA poison != 1..16), h_0 in-kernel.

    k_gemm<<<dim3(4, 16, 4), 256, 0, stream>>>(w_a, base_out, part);
    k_pool<<<dim3(16), 256, 0, stream>>>(part, dist, pooled);
    k_gx<<<dim3(128), 256, 0, stream>>>(pooled, w_ih, b_ih, b_hh, gx);
    k_lstm<<<dim3(32), 256, 0, stream>>>(w_hh, gx, w_cls, b_cls, slots, out);
}